// Round 12
// baseline (116.619 us; speedup 1.0000x reference)
//
#include <hip/hip_runtime.h>
#include <math.h>

#define IH 1024
#define IW 1024
#define NPIX (IH * IW)
#define NW 16   // chunks
#define CH 64   // rows per chunk

// ---------------- Stage 1+2+3 fused: gray -> Sobel -> NMS -> bit-packed ----------
__global__ __launch_bounds__(256) void k_fused(const float* __restrict__ x,
                                               unsigned long long* __restrict__ Sp,
                                               unsigned long long* __restrict__ Wp) {
    __shared__ float g[20][72];
    __shared__ float m[18][68];
    const int bx = blockIdx.x & 15, by = blockIdx.x >> 4;
    const int tid = threadIdx.x;
    const int gi0 = by * 16 - 2, gj0 = bx * 64 - 2;

    for (int e = tid; e < 20 * 68; e += 256) {
        int ly = e / 68, lx = e - ly * 68;
        int gy = gi0 + ly, gxc = gj0 + lx;
        float v = 0.f;
        if ((unsigned)gy < (unsigned)IH && (unsigned)gxc < (unsigned)IW) {
            int p = gy * IW + gxc;
            float r = x[p], gg = x[NPIX + p], b = x[2 * NPIX + p];
            v = __fadd_rn(__fadd_rn(__fmul_rn(r, 0.2989f), __fmul_rn(gg, 0.587f)),
                          __fmul_rn(b, 0.114f));
        }
        g[ly][lx] = v;
    }
    __syncthreads();

    for (int e = tid; e < 18 * 66; e += 256) {
        int ly = e / 66, lx = e - ly * 66;
        float a00 = g[ly][lx],   a01 = g[ly][lx+1],   a02 = g[ly][lx+2];
        float a10 = g[ly+1][lx],                      a12 = g[ly+1][lx+2];
        float a20 = g[ly+2][lx], a21 = g[ly+2][lx+1], a22 = g[ly+2][lx+2];
        float gx = __fmul_rn(-1.f, a00);
        gx = __fadd_rn(gx, a02);
        gx = __fadd_rn(gx, __fmul_rn(-2.f, a10));
        gx = __fadd_rn(gx, __fmul_rn(2.f, a12));
        gx = __fadd_rn(gx, __fmul_rn(-1.f, a20));
        gx = __fadd_rn(gx, a22);
        float gy = a00;
        gy = __fadd_rn(gy, __fmul_rn(2.f, a01));
        gy = __fadd_rn(gy, a02);
        gy = __fadd_rn(gy, __fmul_rn(-1.f, a20));
        gy = __fadd_rn(gy, __fmul_rn(-2.f, a21));
        gy = __fadd_rn(gy, __fmul_rn(-1.f, a22));
        m[ly][lx] = __fsqrt_rn(__fadd_rn(__fmul_rn(gx, gx), __fmul_rn(gy, gy)));
    }
    __syncthreads();

    const int lane = tid & 63;
    const int wv = tid >> 6;
    #pragma unroll
    for (int rr = 0; rr < 4; ++rr) {
        int ti = wv * 4 + rr;
        int i = by * 16 + ti, j = bx * 64 + lane;
        float a00 = g[ti+1][lane+1], a01 = g[ti+1][lane+2], a02 = g[ti+1][lane+3];
        float a10 = g[ti+2][lane+1],                         a12 = g[ti+2][lane+3];
        float a20 = g[ti+3][lane+1], a21 = g[ti+3][lane+2], a22 = g[ti+3][lane+3];
        float gx = __fmul_rn(-1.f, a00);
        gx = __fadd_rn(gx, a02);
        gx = __fadd_rn(gx, __fmul_rn(-2.f, a10));
        gx = __fadd_rn(gx, __fmul_rn(2.f, a12));
        gx = __fadd_rn(gx, __fmul_rn(-1.f, a20));
        gx = __fadd_rn(gx, a22);
        float gy = a00;
        gy = __fadd_rn(gy, __fmul_rn(2.f, a01));
        gy = __fadd_rn(gy, a02);
        gy = __fadd_rn(gy, __fmul_rn(-1.f, a20));
        gy = __fadd_rn(gy, __fmul_rn(-2.f, a21));
        gy = __fadd_rn(gy, __fmul_rn(-1.f, a22));

        float ai = __fmul_rn(atan2f(gy, gx), 57.295779513082320876798154814105f);
        float c = m[ti+1][lane+1];
        float n1, n2;
        if (ai < -22.5f || ai >= 157.5f)      { n1 = m[ti+1][lane];   n2 = m[ti+1][lane+2]; }
        else if (ai < 22.5f)                  { n1 = m[ti][lane+1];   n2 = m[ti+2][lane+1]; }
        else if (ai < 67.5f)                  { n1 = m[ti][lane];     n2 = m[ti+2][lane+2]; }
        else if (ai < 112.5f)                 { n1 = m[ti][lane+1];   n2 = m[ti+2][lane+1]; }
        else                                  { n1 = m[ti][lane+2];   n2 = m[ti+2][lane];   }
        bool border = (i == 0) | (i == IH - 1) | (j == 0) | (j == IW - 1);
        bool keep = (c >= n1) && (c >= n2);
        float supp = keep ? c : 0.f;
        bool sb = !border && (supp >= 50.f);
        bool wb = !border && (supp >= 20.f) && !(supp >= 50.f);
        unsigned long long bs = __ballot(sb);
        unsigned long long bw = __ballot(wb);
        if (lane == 0) {
            Sp[i * 16 + bx] = bs;
            Wp[i * 16 + bx] = bw;
        }
    }
}

// async global->LDS: 64 lanes x 4B = 256 B = TWO consecutive 32-word rows
__device__ __forceinline__ void dma4(const unsigned int* g, unsigned int* l) {
    __builtin_amdgcn_global_load_lds(
        (const __attribute__((address_space(1))) void*)g,
        (__attribute__((address_space(3))) void*)l, 4, 0, 0);
}

// bit row -> 32 floats per lane (lanes 0-31 only; 32-63 are mirrors)
__device__ __forceinline__ void fwrite_row(float* out, int r, int k, int lane,
                                           unsigned int w) {
    if (lane < 32) {
        float4* p = (float4*)(out + r * 1024 + k * 32);
        #pragma unroll
        for (int q = 0; q < 8; ++q) {
            float4 v;
            v.x = ((w >> (4 * q + 0)) & 1u) ? 1.f : 0.f;
            v.y = ((w >> (4 * q + 1)) & 1u) ? 1.f : 0.f;
            v.z = ((w >> (4 * q + 2)) & 1u) ? 1.f : 0.f;
            v.w = ((w >> (4 * q + 3)) & 1u) ? 1.f : 0.f;
            p[q] = v;
        }
    }
}

// One row of the recurrence (verified absmax 0 since R8).
#define CHAIN_STEP(W_, S_, T_)                                                  \
    unsigned int hxp = (prevU << 1) | prevU | ((prevU >> 1) | crp);             \
    unsigned int seed = hxp | (T_);                                             \
    unsigned int P = (W_);                                                      \
    unsigned int G = (S_) | (P & seed);                                         \
    unsigned int A = G | P;                                                     \
    unsigned int AXG = A ^ G;                                                   \
    unsigned int s1v = A + G;                                                   \
    unsigned long long gm = __ballot(s1v < A) & 0xFFFFFFFFull;                  \
    unsigned long long pm = __ballot(s1v == 0xFFFFFFFFu) & 0xFFFFFFFFull;       \
    unsigned long long G0 = __ballot((G & 1u) != 0u);                           \
    unsigned long long P0 = __ballot((P & 1u) != 0u);                           \
    unsigned long long aa = gm | pm;                                            \
    unsigned long long ssum = aa + gm;                                          \
    unsigned long long cvw = ssum ^ aa ^ gm;                                    \
    unsigned long long mlo_o = G0 | (P0 & cvw);                                 \
    unsigned int cin = (((unsigned int)cvw) >> k) & 1u;                         \
    unsigned int ovb = ((((unsigned int)(cvw >> 1)) >> k) & 1u) << 31;          \
    unsigned int s2 = s1v + cin;                                                \
    unsigned int outv = ((s2 ^ AXG) >> 1) | ovb;                                \
    unsigned int rtP = ((((unsigned int)(mlo_o >> 1)) >> k) & 1u) << 31;        \
    crp = cin | rtP;                                                            \
    prevU = outv;

// STAT_r = Rx(S_r) | Hx(S_{r+1})  (R8 PBODY formula, verified)
#define MKT(T_, SA_, SN_) {                                                     \
    unsigned long long mla = __ballot(((SA_) & 1u) != 0u);                      \
    unsigned long long mln = __ballot(((SN_) & 1u) != 0u);                      \
    unsigned long long mhn = __ballot(((SN_) >> 31) != 0u);                     \
    unsigned int rxC = (SA_) | ((SA_) >> 1)                                     \
                     | (((((unsigned int)(mla >> 1)) >> k) & 1u) << 31);        \
    unsigned int hxN = (SN_) | ((SN_) << 1) | ((SN_) >> 1)                      \
                     | ((((unsigned int)(mhn << 1)) >> k) & 1u)                 \
                     | (((((unsigned int)(mln >> 1)) >> k) & 1u) << 31);        \
    T_ = rxC | hxN; }

// ---------------- Stage 4a: parallel speculative solve (one wave per CU) -------
#define SPEC_ROW(dd) {                                                          \
    const int d = (dd);                                                         \
    const int r = r0 + d;                                                       \
    unsigned int Wv = ringW[d & 7][k];                                          \
    unsigned int RS = (d < 63) ? ringS[(d + 1) & 7][k] : Stail;                 \
    unsigned long long mhiN = __ballot((RS >> 31) != 0u);                       \
    unsigned long long mloN = __ballot((RS & 1u) != 0u);                        \
    unsigned int rxC = SA | (SA >> 1)                                           \
                     | (((((unsigned int)(mloA >> 1)) >> k) & 1u) << 31);       \
    unsigned int hxN = RS | (RS << 1) | (RS >> 1)                               \
                     | ((((unsigned int)(mhiN << 1)) >> k) & 1u)                \
                     | (((((unsigned int)(mloN >> 1)) >> k) & 1u) << 31);       \
    unsigned int Tv = rxC | hxN;                                                \
    CHAIN_STEP(Wv, SA, Tv)                                                      \
    if (r <= 1022) {                                                            \
        Osp[r * 32 + k] = outv;                                                 \
        fwrite_row(out, r, k, lane, outv);                                      \
    }                                                                           \
    SA = RS; mloA = mloN;                                                       \
}

__global__ __launch_bounds__(64, 1) void k_spec(const unsigned int* __restrict__ Sp,
                                                const unsigned int* __restrict__ Wp,
                                                unsigned int* __restrict__ Osp,
                                                float* __restrict__ out) {
    __shared__ unsigned int ringW[8][32];
    __shared__ unsigned int ringS[8][32];
    const int c = blockIdx.x;
    const int lane = threadIdx.x;
    const int k = lane & 31;
    const int r0 = c * CH + 1;

    // prestage groups 0..2 (each dma covers 2 rows)
    #pragma unroll
    for (int g = 0; g < 3; ++g) {
        dma4(Wp + (r0 + 2 * g) * 32 + lane, &ringW[(2 * g) & 7][0]);
        dma4(Sp + (r0 + 2 * g) * 32 + lane, &ringS[(2 * g) & 7][0]);
    }
    unsigned int prevU = Sp[(r0 - 1) * 32 + k];       // static lower bound
    int tl = r0 + 64; if (tl > 1023) tl = 1023;
    unsigned int Stail = Sp[tl * 32 + k];             // S_{r0+64} for last STAT
    unsigned int crp;
    {
        unsigned long long mh = __ballot((prevU >> 31) != 0u);
        unsigned long long ml = __ballot((prevU & 1u) != 0u);
        crp = ((((unsigned int)(mh << 1)) >> k) & 1u)
            | (((((unsigned int)(ml >> 1)) >> k) & 1u) << 31);
    }
    if (c == 0) fwrite_row(out, 0, k, lane, 0u);       // border float rows
    if (c == NW - 1) fwrite_row(out, 1023, k, lane, 0u);

    asm volatile("s_waitcnt vmcnt(4)" ::: "memory");   // groups 0,1 done
    unsigned int SA = ringS[0][k];
    unsigned long long mloA = __ballot((SA & 1u) != 0u);

    #pragma unroll 1
    for (int t = 0; t < 32; ++t) {
        if (t < 29) {
            int g2 = t + 3;
            dma4(Wp + (r0 + 2 * g2) * 32 + lane, &ringW[(2 * g2) & 7][0]);
            dma4(Sp + (r0 + 2 * g2) * 32 + lane, &ringS[(2 * g2) & 7][0]);
            asm volatile("s_waitcnt vmcnt(4)" ::: "memory");  // group t+1 done
        } else if (t == 29) {
            asm volatile("s_waitcnt vmcnt(2)" ::: "memory");  // group 30 done
        } else {
            asm volatile("s_waitcnt vmcnt(0)" ::: "memory");  // group 31 done
        }
        SPEC_ROW(2 * t)
        SPEC_ROW(2 * t + 1)
    }
}

// ---------------- Stage 4b: sequential fixup (16 waves, one workgroup) ---------
#define FIX_STEP(d, W_, S_, T_, SP_) if (!done) {                               \
    const int r = r0 + (d);                                                     \
    CHAIN_STEP(W_, S_, T_)                                                      \
    unsigned long long df = __ballot(outv != (SP_));                            \
    if ((df & 0xFFFFFFFFull) == 0ull) { done = true; converged = true; }        \
    else { Osp[r * 32 + k] = outv; fwrite_row(out, r, k, lane, outv); }         \
}

__global__ __launch_bounds__(1024) void k_fix(const unsigned int* __restrict__ Sp,
                                              const unsigned int* __restrict__ Wp,
                                              unsigned int* __restrict__ Osp,
                                              float* __restrict__ out) {
    __shared__ unsigned int prevRowLds[NW][32];
    __shared__ unsigned int fixedUpTo;
    const int tid = threadIdx.x;
    const int c = tid >> 6;
    const int lane = tid & 63;
    const int k = lane & 31;
    const int r0 = c * CH + 1;

    if (tid == 0) fixedUpTo = 0u;
    __syncthreads();

    // prestage depth-8 working set into registers (before waiting for the turn)
    const unsigned int* Sb = Sp + r0 * 32 + k;
    unsigned int S0 = Sb[0],   S1 = Sb[32],  S2 = Sb[64],  S3 = Sb[96],
                 S4 = Sb[128], S5 = Sb[160], S6 = Sb[192], S7 = Sb[224],
                 S8 = Sb[256];
    const unsigned int* Wb = Wp + r0 * 32 + k;
    unsigned int W0 = Wb[0],   W1 = Wb[32],  W2 = Wb[64],  W3 = Wb[96],
                 W4 = Wb[128], W5 = Wb[160], W6 = Wb[192], W7 = Wb[224];
    const unsigned int* Ob = Osp + r0 * 32 + k;
    unsigned int p0 = Ob[0],   p1 = Ob[32],  p2 = Ob[64],  p3 = Ob[96],
                 p4 = Ob[128], p5 = Ob[160], p6 = Ob[192], p7 = Ob[224];
    int lr = r0 + 63; if (lr > 1022) lr = 1022;
    unsigned int p1last = Osp[lr * 32 + k];   // spec last row (true if converged)
    unsigned int T0, T1, T2, T3, T4, T5, T6, T7;
    MKT(T0, S0, S1) MKT(T1, S1, S2) MKT(T2, S2, S3) MKT(T3, S3, S4)
    MKT(T4, S4, S5) MKT(T5, S5, S6) MKT(T6, S6, S7) MKT(T7, S7, S8)

    unsigned int bd = p1last;
    bool done = false, converged = false;
    unsigned int prevU = 0u, crp = 0u;
    if (c > 0) {
        while (*((volatile unsigned int*)&fixedUpTo) != (unsigned int)c)
            __builtin_amdgcn_s_sleep(1);
        asm volatile("" ::: "memory");
        prevU = prevRowLds[c][k];            // true last row of chunk c-1
        {
            unsigned long long mh = __ballot((prevU >> 31) != 0u);
            unsigned long long ml = __ballot((prevU & 1u) != 0u);
            crp = ((((unsigned int)(mh << 1)) >> k) & 1u)
                | (((((unsigned int)(ml >> 1)) >> k) & 1u) << 31);
        }
        FIX_STEP(0, W0, S0, T0, p0) FIX_STEP(1, W1, S1, T1, p1)
        FIX_STEP(2, W2, S2, T2, p2) FIX_STEP(3, W3, S3, T3, p3)
        FIX_STEP(4, W4, S4, T4, p4) FIX_STEP(5, W5, S5, T5, p5)
        FIX_STEP(6, W6, S6, T6, p6) FIX_STEP(7, W7, S7, T7, p7)
        if (!done) {
            #pragma unroll 1
            for (int d = 8; d < CH; ++d) {     // rare deep path: global loads
                int r = r0 + d;
                if (r > 1022) break;
                unsigned int Wv = Wp[r * 32 + k];
                unsigned int Sv = Sp[r * 32 + k];
                int rn = r + 1; if (rn > 1023) rn = 1023;
                unsigned int Sn = Sp[rn * 32 + k];
                unsigned int sp = Osp[r * 32 + k];
                unsigned int Tv;
                MKT(Tv, Sv, Sn)
                CHAIN_STEP(Wv, Sv, Tv)
                unsigned long long df = __ballot(outv != sp);
                if ((df & 0xFFFFFFFFull) == 0ull) { converged = true; break; }
                Osp[r * 32 + k] = outv;
                fwrite_row(out, r, k, lane, outv);
            }
        }
        bd = converged ? p1last : prevU;     // true row r0+63 either way
    }
    if (c < NW - 1) prevRowLds[c + 1][k] = bd;
    asm volatile("s_waitcnt lgkmcnt(0)" ::: "memory");
    if (lane == 0) *((volatile unsigned int*)&fixedUpTo) = (unsigned int)(c + 1);
}

extern "C" void kernel_launch(void* const* d_in, const int* in_sizes, int n_in,
                              void* d_out, int out_size, void* d_ws, size_t ws_size,
                              hipStream_t stream) {
    const float* x = (const float*)d_in[0];
    float* out = (float*)d_out;
    char* ws = (char*)d_ws;

    unsigned long long* Sp = (unsigned long long*)(ws);
    unsigned long long* Wp = (unsigned long long*)(ws + 128u * 1024u);
    unsigned int*      Osp = (unsigned int*)(ws + 256u * 1024u);

    k_fused<<<1024, 256, 0, stream>>>(x, Sp, Wp);
    k_spec<<<NW, 64, 0, stream>>>((const unsigned int*)Sp, (const unsigned int*)Wp,
                                  Osp, out);
    k_fix<<<1, 1024, 0, stream>>>((const unsigned int*)Sp, (const unsigned int*)Wp,
                                  Osp, out);
}

// Round 13
// 97.083 us; speedup vs baseline: 1.2012x; 1.2012x over previous
//
#include <hip/hip_runtime.h>
#include <math.h>

#define IH 1024
#define IW 1024
#define NPIX (IH * IW)
#define NW 16   // chunks
#define CH 64   // rows per chunk

// ---------------- Stage 1+2+3 fused: gray -> Sobel -> NMS -> bit-packed ----------
__global__ __launch_bounds__(256) void k_fused(const float* __restrict__ x,
                                               unsigned long long* __restrict__ Sp,
                                               unsigned long long* __restrict__ Wp) {
    __shared__ float g[20][72];
    __shared__ float m[18][68];
    const int bx = blockIdx.x & 15, by = blockIdx.x >> 4;
    const int tid = threadIdx.x;
    const int gi0 = by * 16 - 2, gj0 = bx * 64 - 2;

    for (int e = tid; e < 20 * 68; e += 256) {
        int ly = e / 68, lx = e - ly * 68;
        int gy = gi0 + ly, gxc = gj0 + lx;
        float v = 0.f;
        if ((unsigned)gy < (unsigned)IH && (unsigned)gxc < (unsigned)IW) {
            int p = gy * IW + gxc;
            float r = x[p], gg = x[NPIX + p], b = x[2 * NPIX + p];
            v = __fadd_rn(__fadd_rn(__fmul_rn(r, 0.2989f), __fmul_rn(gg, 0.587f)),
                          __fmul_rn(b, 0.114f));
        }
        g[ly][lx] = v;
    }
    __syncthreads();

    for (int e = tid; e < 18 * 66; e += 256) {
        int ly = e / 66, lx = e - ly * 66;
        float a00 = g[ly][lx],   a01 = g[ly][lx+1],   a02 = g[ly][lx+2];
        float a10 = g[ly+1][lx],                      a12 = g[ly+1][lx+2];
        float a20 = g[ly+2][lx], a21 = g[ly+2][lx+1], a22 = g[ly+2][lx+2];
        float gx = __fmul_rn(-1.f, a00);
        gx = __fadd_rn(gx, a02);
        gx = __fadd_rn(gx, __fmul_rn(-2.f, a10));
        gx = __fadd_rn(gx, __fmul_rn(2.f, a12));
        gx = __fadd_rn(gx, __fmul_rn(-1.f, a20));
        gx = __fadd_rn(gx, a22);
        float gy = a00;
        gy = __fadd_rn(gy, __fmul_rn(2.f, a01));
        gy = __fadd_rn(gy, a02);
        gy = __fadd_rn(gy, __fmul_rn(-1.f, a20));
        gy = __fadd_rn(gy, __fmul_rn(-2.f, a21));
        gy = __fadd_rn(gy, __fmul_rn(-1.f, a22));
        m[ly][lx] = __fsqrt_rn(__fadd_rn(__fmul_rn(gx, gx), __fmul_rn(gy, gy)));
    }
    __syncthreads();

    const int lane = tid & 63;
    const int wv = tid >> 6;
    #pragma unroll
    for (int rr = 0; rr < 4; ++rr) {
        int ti = wv * 4 + rr;
        int i = by * 16 + ti, j = bx * 64 + lane;
        float a00 = g[ti+1][lane+1], a01 = g[ti+1][lane+2], a02 = g[ti+1][lane+3];
        float a10 = g[ti+2][lane+1],                         a12 = g[ti+2][lane+3];
        float a20 = g[ti+3][lane+1], a21 = g[ti+3][lane+2], a22 = g[ti+3][lane+3];
        float gx = __fmul_rn(-1.f, a00);
        gx = __fadd_rn(gx, a02);
        gx = __fadd_rn(gx, __fmul_rn(-2.f, a10));
        gx = __fadd_rn(gx, __fmul_rn(2.f, a12));
        gx = __fadd_rn(gx, __fmul_rn(-1.f, a20));
        gx = __fadd_rn(gx, a22);
        float gy = a00;
        gy = __fadd_rn(gy, __fmul_rn(2.f, a01));
        gy = __fadd_rn(gy, a02);
        gy = __fadd_rn(gy, __fmul_rn(-1.f, a20));
        gy = __fadd_rn(gy, __fmul_rn(-2.f, a21));
        gy = __fadd_rn(gy, __fmul_rn(-1.f, a22));

        float ai = __fmul_rn(atan2f(gy, gx), 57.295779513082320876798154814105f);
        float c = m[ti+1][lane+1];
        float n1, n2;
        if (ai < -22.5f || ai >= 157.5f)      { n1 = m[ti+1][lane];   n2 = m[ti+1][lane+2]; }
        else if (ai < 22.5f)                  { n1 = m[ti][lane+1];   n2 = m[ti+2][lane+1]; }
        else if (ai < 67.5f)                  { n1 = m[ti][lane];     n2 = m[ti+2][lane+2]; }
        else if (ai < 112.5f)                 { n1 = m[ti][lane+1];   n2 = m[ti+2][lane+1]; }
        else                                  { n1 = m[ti][lane+2];   n2 = m[ti+2][lane];   }
        bool border = (i == 0) | (i == IH - 1) | (j == 0) | (j == IW - 1);
        bool keep = (c >= n1) && (c >= n2);
        float supp = keep ? c : 0.f;
        bool sb = !border && (supp >= 50.f);
        bool wb = !border && (supp >= 20.f) && !(supp >= 50.f);
        unsigned long long bs = __ballot(sb);
        unsigned long long bw = __ballot(wb);
        if (lane == 0) {
            Sp[i * 16 + bx] = bs;
            Wp[i * 16 + bx] = bw;
        }
    }
}

// async global->LDS: 64 lanes x 4B = 256 B = TWO consecutive 32-word rows
__device__ __forceinline__ void dma4(const unsigned int* g, unsigned int* l) {
    __builtin_amdgcn_global_load_lds(
        (const __attribute__((address_space(1))) void*)g,
        (__attribute__((address_space(3))) void*)l, 4, 0, 0);
}

// One row of the recurrence (verified absmax 0 since R8).
#define CHAIN_STEP(W_, S_, T_)                                                  \
    unsigned int hxp = (prevU << 1) | prevU | ((prevU >> 1) | crp);             \
    unsigned int seed = hxp | (T_);                                             \
    unsigned int P = (W_);                                                      \
    unsigned int G = (S_) | (P & seed);                                         \
    unsigned int A = G | P;                                                     \
    unsigned int AXG = A ^ G;                                                   \
    unsigned int s1v = A + G;                                                   \
    unsigned long long gm = __ballot(s1v < A) & 0xFFFFFFFFull;                  \
    unsigned long long pm = __ballot(s1v == 0xFFFFFFFFu) & 0xFFFFFFFFull;       \
    unsigned long long G0 = __ballot((G & 1u) != 0u);                           \
    unsigned long long P0 = __ballot((P & 1u) != 0u);                           \
    unsigned long long aa = gm | pm;                                            \
    unsigned long long ssum = aa + gm;                                          \
    unsigned long long cvw = ssum ^ aa ^ gm;                                    \
    unsigned long long mlo_o = G0 | (P0 & cvw);                                 \
    unsigned int cin = (((unsigned int)cvw) >> k) & 1u;                         \
    unsigned int ovb = ((((unsigned int)(cvw >> 1)) >> k) & 1u) << 31;          \
    unsigned int s2 = s1v + cin;                                                \
    unsigned int outv = ((s2 ^ AXG) >> 1) | ovb;                                \
    unsigned int rtP = ((((unsigned int)(mlo_o >> 1)) >> k) & 1u) << 31;        \
    crp = cin | rtP;                                                            \
    prevU = outv;

// STAT_r = Rx(S_r) | Hx(S_{r+1})  (verified)
#define MKT(T_, SA_, SN_) {                                                     \
    unsigned long long mla = __ballot(((SA_) & 1u) != 0u);                      \
    unsigned long long mln = __ballot(((SN_) & 1u) != 0u);                      \
    unsigned long long mhn = __ballot(((SN_) >> 31) != 0u);                     \
    unsigned int rxC = (SA_) | ((SA_) >> 1)                                     \
                     | (((((unsigned int)(mla >> 1)) >> k) & 1u) << 31);        \
    unsigned int hxN = (SN_) | ((SN_) << 1) | ((SN_) >> 1)                      \
                     | ((((unsigned int)(mhn << 1)) >> k) & 1u)                 \
                     | (((((unsigned int)(mln >> 1)) >> k) & 1u) << 31);        \
    T_ = rxC | hxN; }

// ---------------- Stage 4a: parallel speculative solve (one wave per CU) -------
// Bits only — NO float output here (R12 regression: 4 MB from 16 waves = 46 µs).
#define SPEC_ROW(dd) {                                                          \
    const int d = (dd);                                                         \
    const int r = r0 + d;                                                       \
    unsigned int Wv = ringW[d & 7][k];                                          \
    unsigned int RS = (d < 63) ? ringS[(d + 1) & 7][k] : Stail;                 \
    unsigned long long mhiN = __ballot((RS >> 31) != 0u);                       \
    unsigned long long mloN = __ballot((RS & 1u) != 0u);                        \
    unsigned int rxC = SA | (SA >> 1)                                           \
                     | (((((unsigned int)(mloA >> 1)) >> k) & 1u) << 31);       \
    unsigned int hxN = RS | (RS << 1) | (RS >> 1)                               \
                     | ((((unsigned int)(mhiN << 1)) >> k) & 1u)                \
                     | (((((unsigned int)(mloN >> 1)) >> k) & 1u) << 31);       \
    unsigned int Tv = rxC | hxN;                                                \
    CHAIN_STEP(Wv, SA, Tv)                                                      \
    if (r <= 1022) Osp[r * 32 + k] = outv;                                      \
    SA = RS; mloA = mloN;                                                       \
}

__global__ __launch_bounds__(64, 1) void k_spec(const unsigned int* __restrict__ Sp,
                                                const unsigned int* __restrict__ Wp,
                                                unsigned int* __restrict__ Osp) {
    __shared__ unsigned int ringW[8][32];
    __shared__ unsigned int ringS[8][32];
    const int c = blockIdx.x;
    const int lane = threadIdx.x;
    const int k = lane & 31;
    const int r0 = c * CH + 1;

    #pragma unroll
    for (int g = 0; g < 3; ++g) {
        dma4(Wp + (r0 + 2 * g) * 32 + lane, &ringW[(2 * g) & 7][0]);
        dma4(Sp + (r0 + 2 * g) * 32 + lane, &ringS[(2 * g) & 7][0]);
    }
    unsigned int prevU = Sp[(r0 - 1) * 32 + k];       // static lower bound
    int tl = r0 + 64; if (tl > 1023) tl = 1023;
    unsigned int Stail = Sp[tl * 32 + k];             // S_{r0+64} for last STAT
    unsigned int crp;
    {
        unsigned long long mh = __ballot((prevU >> 31) != 0u);
        unsigned long long ml = __ballot((prevU & 1u) != 0u);
        crp = ((((unsigned int)(mh << 1)) >> k) & 1u)
            | (((((unsigned int)(ml >> 1)) >> k) & 1u) << 31);
    }
    // borders: zero the bit rows (ws is 0xAA-poisoned; k_unpack reads them)
    if (c == 0 && lane < 32) Osp[k] = 0u;
    if (c == NW - 1 && lane < 32) Osp[1023 * 32 + k] = 0u;

    asm volatile("s_waitcnt vmcnt(4)" ::: "memory");   // groups 0,1 done
    unsigned int SA = ringS[0][k];
    unsigned long long mloA = __ballot((SA & 1u) != 0u);

    #pragma unroll 1
    for (int t = 0; t < 32; ++t) {
        if (t < 29) {
            int g2 = t + 3;
            dma4(Wp + (r0 + 2 * g2) * 32 + lane, &ringW[(2 * g2) & 7][0]);
            dma4(Sp + (r0 + 2 * g2) * 32 + lane, &ringS[(2 * g2) & 7][0]);
            asm volatile("s_waitcnt vmcnt(4)" ::: "memory");  // group t+1 done
        } else if (t == 29) {
            asm volatile("s_waitcnt vmcnt(2)" ::: "memory");  // group 30 done
        } else {
            asm volatile("s_waitcnt vmcnt(0)" ::: "memory");  // group 31 done
        }
        SPEC_ROW(2 * t)
        SPEC_ROW(2 * t + 1)
    }
}

// ---------------- Stage 4b: sequential fixup (16 waves, one workgroup) ---------
#define FIX_STEP(d, W_, S_, T_, SP_) if (!done) {                               \
    const int r = r0 + (d);                                                     \
    CHAIN_STEP(W_, S_, T_)                                                      \
    unsigned long long df = __ballot(outv != (SP_));                            \
    if ((df & 0xFFFFFFFFull) == 0ull) { done = true; converged = true; }        \
    else Osp[r * 32 + k] = outv;                                                \
}

__global__ __launch_bounds__(1024) void k_fix(const unsigned int* __restrict__ Sp,
                                              const unsigned int* __restrict__ Wp,
                                              unsigned int* __restrict__ Osp) {
    __shared__ unsigned int prevRowLds[NW][32];
    __shared__ unsigned int fixedUpTo;
    const int tid = threadIdx.x;
    const int c = tid >> 6;
    const int lane = tid & 63;
    const int k = lane & 31;
    const int r0 = c * CH + 1;

    if (tid == 0) fixedUpTo = 0u;
    __syncthreads();

    // prestage depth-8 working set into registers (before waiting for the turn)
    const unsigned int* Sb = Sp + r0 * 32 + k;
    unsigned int S0 = Sb[0],   S1 = Sb[32],  S2 = Sb[64],  S3 = Sb[96],
                 S4 = Sb[128], S5 = Sb[160], S6 = Sb[192], S7 = Sb[224],
                 S8 = Sb[256];
    const unsigned int* Wb = Wp + r0 * 32 + k;
    unsigned int W0 = Wb[0],   W1 = Wb[32],  W2 = Wb[64],  W3 = Wb[96],
                 W4 = Wb[128], W5 = Wb[160], W6 = Wb[192], W7 = Wb[224];
    const unsigned int* Ob = Osp + r0 * 32 + k;
    unsigned int p0 = Ob[0],   p1 = Ob[32],  p2 = Ob[64],  p3 = Ob[96],
                 p4 = Ob[128], p5 = Ob[160], p6 = Ob[192], p7 = Ob[224];
    int lr = r0 + 63; if (lr > 1022) lr = 1022;
    unsigned int p1last = Osp[lr * 32 + k];   // spec last row (true if converged)
    unsigned int T0, T1, T2, T3, T4, T5, T6, T7;
    MKT(T0, S0, S1) MKT(T1, S1, S2) MKT(T2, S2, S3) MKT(T3, S3, S4)
    MKT(T4, S4, S5) MKT(T5, S5, S6) MKT(T6, S6, S7) MKT(T7, S7, S8)

    unsigned int bd = p1last;
    bool done = false, converged = false;
    unsigned int prevU = 0u, crp = 0u;
    if (c > 0) {
        while (*((volatile unsigned int*)&fixedUpTo) != (unsigned int)c)
            __builtin_amdgcn_s_sleep(1);
        asm volatile("" ::: "memory");
        prevU = prevRowLds[c][k];            // true last row of chunk c-1
        {
            unsigned long long mh = __ballot((prevU >> 31) != 0u);
            unsigned long long ml = __ballot((prevU & 1u) != 0u);
            crp = ((((unsigned int)(mh << 1)) >> k) & 1u)
                | (((((unsigned int)(ml >> 1)) >> k) & 1u) << 31);
        }
        FIX_STEP(0, W0, S0, T0, p0) FIX_STEP(1, W1, S1, T1, p1)
        FIX_STEP(2, W2, S2, T2, p2) FIX_STEP(3, W3, S3, T3, p3)
        FIX_STEP(4, W4, S4, T4, p4) FIX_STEP(5, W5, S5, T5, p5)
        FIX_STEP(6, W6, S6, T6, p6) FIX_STEP(7, W7, S7, T7, p7)
        if (!done) {
            #pragma unroll 1
            for (int d = 8; d < CH; ++d) {     // rare deep path: global loads
                int r = r0 + d;
                if (r > 1022) break;
                unsigned int Wv = Wp[r * 32 + k];
                unsigned int Sv = Sp[r * 32 + k];
                int rn = r + 1; if (rn > 1023) rn = 1023;
                unsigned int Sn = Sp[rn * 32 + k];
                unsigned int sp = Osp[r * 32 + k];
                unsigned int Tv;
                MKT(Tv, Sv, Sn)
                CHAIN_STEP(Wv, Sv, Tv)
                unsigned long long df = __ballot(outv != sp);
                if ((df & 0xFFFFFFFFull) == 0ull) { converged = true; break; }
                Osp[r * 32 + k] = outv;
            }
        }
        bd = converged ? p1last : prevU;     // true row r0+63 either way
    }
    if (c < NW - 1) prevRowLds[c + 1][k] = bd;
    asm volatile("s_waitcnt lgkmcnt(0)" ::: "memory");
    if (lane == 0) *((volatile unsigned int*)&fixedUpTo) = (unsigned int)(c + 1);
}

// ---------------- Stage 5: unpack bits -> float (full parallelism) ----------------
__global__ __launch_bounds__(256) void k_unpack(const unsigned int* __restrict__ Osp,
                                                float* __restrict__ out) {
    int t = blockIdx.x * blockDim.x + threadIdx.x;   // 1 thread = 4 px
    int px = t * 4;
    if (px >= NPIX) return;
    unsigned int w = Osp[px >> 5];
    int sh = px & 31;
    float4 v;
    v.x = ((w >> (sh + 0)) & 1u) ? 1.f : 0.f;
    v.y = ((w >> (sh + 1)) & 1u) ? 1.f : 0.f;
    v.z = ((w >> (sh + 2)) & 1u) ? 1.f : 0.f;
    v.w = ((w >> (sh + 3)) & 1u) ? 1.f : 0.f;
    *((float4*)(out + px)) = v;
}

extern "C" void kernel_launch(void* const* d_in, const int* in_sizes, int n_in,
                              void* d_out, int out_size, void* d_ws, size_t ws_size,
                              hipStream_t stream) {
    const float* x = (const float*)d_in[0];
    float* out = (float*)d_out;
    char* ws = (char*)d_ws;

    unsigned long long* Sp = (unsigned long long*)(ws);
    unsigned long long* Wp = (unsigned long long*)(ws + 128u * 1024u);
    unsigned int*      Osp = (unsigned int*)(ws + 256u * 1024u);

    k_fused<<<1024, 256, 0, stream>>>(x, Sp, Wp);
    k_spec<<<NW, 64, 0, stream>>>((const unsigned int*)Sp, (const unsigned int*)Wp,
                                  Osp);
    k_fix<<<1, 1024, 0, stream>>>((const unsigned int*)Sp, (const unsigned int*)Wp,
                                  Osp);
    k_unpack<<<1024, 256, 0, stream>>>((const unsigned int*)Osp, out);
}